// Round 4
// baseline (197.475 us; speedup 1.0000x reference)
//
#include <hip/hip_runtime.h>

// Problem constants
#define BATCH 8
#define HH 56
#define WW 56
#define NPOS (BATCH*HH*WW)   // 25088
#define C 256
#define P 32
#define D 4
#define J 128
#define EPS 1e-3f
#define H2S 136   // h2s LDS stride in shorts: >=128, 272B rows, 2-way banks only

typedef __attribute__((ext_vector_type(8))) short bf16x8_t;
typedef __attribute__((ext_vector_type(4))) float f32x4_t;

__device__ __forceinline__ unsigned short f2bf(float f) {
    union { float f; unsigned int i; } v; v.f = f;
    unsigned int r = v.i + 0x7fffu + ((v.i >> 16) & 1u);   // RNE
    return (unsigned short)(r >> 16);
}
__device__ __forceinline__ uint2 pack4_trunc(float4 v) {
    uint2 r;
    r.x = __builtin_amdgcn_perm(__float_as_uint(v.y), __float_as_uint(v.x), 0x07060302u);
    r.y = __builtin_amdgcn_perm(__float_as_uint(v.w), __float_as_uint(v.z), 0x07060302u);
    return r;
}

// ---------------------------------------------------------------------------
// Fold BN into conv weights/biases (unchanged).
// ---------------------------------------------------------------------------
__global__ __launch_bounds__(256) void fold_params(
    const float* __restrict__ W1, const float* __restrict__ B1,
    const float* __restrict__ W2, const float* __restrict__ B2,
    const float* __restrict__ W3, const float* __restrict__ B3,
    const float* __restrict__ G1, const float* __restrict__ Be1,
    const float* __restrict__ M1, const float* __restrict__ V1,
    const float* __restrict__ G2, const float* __restrict__ Be2,
    const float* __restrict__ M2, const float* __restrict__ V2,
    const float* __restrict__ G3, const float* __restrict__ Be3,
    const float* __restrict__ M3, const float* __restrict__ V3,
    unsigned short* __restrict__ W1bf, float* __restrict__ b1f,
    float* __restrict__ w2q, float* __restrict__ b2t,
    unsigned short* __restrict__ WB, unsigned short* __restrict__ zb)
{
    int idx = blockIdx.x * 256 + threadIdx.x;

    if (idx < C*J) {                       // W1bf[j][c]
        int j = idx >> 8, c = idx & 255;
        int p = j >> 2, d = j & 3;
        float s = G1[j] * rsqrtf(V1[j] + EPS);
        W1bf[idx] = f2bf(W1[(p*C + c)*D + d] * s);
        return;
    }
    idx -= C*J;
    if (idx < J) {
        float s = G1[idx] * rsqrtf(V1[idx] + EPS);
        b1f[idx] = B1[idx] * s + Be1[idx] - M1[idx] * s;
        return;
    }
    idx -= J;
    if (idx < 9*D*D*P) {                   // w2q [(k9*4+di)*128 + p*4 + do]
        int do_ = idx & 3, p = (idx >> 2) & 31;
        int r2 = idx >> 7, di = r2 & 3, k9 = r2 >> 2;
        int j = p*4 + do_;
        float s = G2[j] * rsqrtf(V2[j] + EPS);
        w2q[idx] = W2[((p*9 + k9)*4 + di)*4 + do_] * s;
        return;
    }
    idx -= 9*D*D*P;
    if (idx < J) {                         // b2t[do][p]
        int do_ = idx >> 5, p = idx & 31;
        int j = p*4 + do_;
        float s = G2[j] * rsqrtf(V2[j] + EPS);
        b2t[idx] = B2[j] * s + Be2[j] - M2[j] * s;
        return;
    }
    idx -= J;
    if (idx < P*C*8) {                     // WB[p][c][s] = {w0..w3, bias, 0,0,0}
        int s8 = idx & 7;
        int c = (idx >> 3) & 255;
        int p = idx >> 11;
        float sc = G3[p*C + c] * rsqrtf(V3[p*C + c] + EPS);
        float v = 0.f;
        if (s8 < 4)       v = W3[(p*D + s8)*C + c] * sc;
        else if (s8 == 4) v = B3[p*C + c] * sc + Be3[p*C + c] - M3[p*C + c] * sc;
        WB[idx] = f2bf(v);
        return;
    }
    idx -= P*C*8;
    if (idx < 8) { zb[idx] = 0; return; }  // 16B zero block
}

// ---------------------------------------------------------------------------
// Fully fused block, occupancy version. LDS = h1L + h2s only (25.6 KB ->
// 6 blocks/CU). Stage-1 B-operand loaded directly from global x (L1/L2-hot,
// 4-wave redundant); stage-2 weights/biases read from L2-hot global.
// Grid: 8*14*7 = 784 blocks, 256 thr; all blocks co-resident.
// ---------------------------------------------------------------------------
__global__ __launch_bounds__(256) void fused_all(
    const float* __restrict__ x, const unsigned short* __restrict__ W1bf,
    const float* __restrict__ b1f, const float* __restrict__ w2q,
    const float* __restrict__ b2t, const unsigned short* __restrict__ WB,
    const unsigned short* __restrict__ zb, float* __restrict__ out)
{
    __shared__ unsigned short h1L[64*132];   // 16.9 KB  [pos][j], stride 132
    __shared__ unsigned short h2s[32*H2S];   // 8.7 KB   [pos][j], stride 136

    const int tid = threadIdx.x;
    int bxx = blockIdx.x;
    const int xb = bxx % 7;  bxx /= 7;
    const int yb = bxx % 14; const int b = bxx / 14;
    const int wid = tid >> 6, l = tid & 63, l15 = l & 15, quad = l >> 4;
    const int j0w = wid * 32;

    // W1 A-frags (global, L2-hot)
    union bu { uint4 u; bf16x8_t v; };
    bu aw[2][8];
#pragma unroll
    for (int jf = 0; jf < 2; ++jf) {
        int row = j0w + jf*16 + l15;
#pragma unroll
        for (int kc = 0; kc < 8; ++kc)
            aw[jf][kc].u = *(const uint4*)&W1bf[row*C + kc*32 + quad*8];
    }

    // Phase B: s1 GEMM. B-operand: per-lane direct global load of x row
    // (position = l15 within mt-tile), fp32->bf16 pack in regs. Invalid
    // (halo OOB) lanes clamp to row 0 and are zeroed by the h1L write mask
    // (MFMA output column c depends only on B column c).
#pragma unroll
    for (int mt = 0; mt < 4; ++mt) {
        const int row = mt*16 + l15;         // halo pos (B col)
        int hy = (row * 205) >> 11;          // row/10 for row in [0,64)
        int hx = row - hy*10;
        int gy = yb*4 + hy - 1, gx = xb*8 + hx - 1;
        const bool valid = (row < 60) & (gy >= 0) & (gy < HH) & (gx >= 0) & (gx < WW);
        const unsigned mask = valid ? 0xFFFFFFFFu : 0u;
        const size_t n = valid ? (size_t)((b*HH + gy)*WW + gx) : (size_t)0;
        const float* xp = &x[n*C + quad*8];

        f32x4_t acc0 = (f32x4_t){0.f,0.f,0.f,0.f};
        f32x4_t acc1 = (f32x4_t){0.f,0.f,0.f,0.f};
#pragma unroll
        for (int kc = 0; kc < 8; ++kc) {
            float4 v0 = *(const float4*)(xp + kc*32);
            float4 v1 = *(const float4*)(xp + kc*32 + 4);
            uint2 p0 = pack4_trunc(v0), p1 = pack4_trunc(v1);
            union { uint4 u; bf16x8_t v; } bb;
            bb.u.x = p0.x; bb.u.y = p0.y; bb.u.z = p1.x; bb.u.w = p1.y;
            acc0 = __builtin_amdgcn_mfma_f32_16x16x32_bf16(aw[0][kc].v, bb.v, acc0, 0, 0, 0);
            acc1 = __builtin_amdgcn_mfma_f32_16x16x32_bf16(aw[1][kc].v, bb.v, acc1, 0, 0, 0);
        }
#pragma unroll
        for (int jf = 0; jf < 2; ++jf) {
            const f32x4_t a = jf ? acc1 : acc0;
            int jb = j0w + jf*16 + quad*4;
            float4 bias = *(const float4*)&b1f[jb];   // global, L2-hot
            float v0 = fmaxf(a[0] + bias.x, 0.f);
            float v1 = fmaxf(a[1] + bias.y, 0.f);
            float v2 = fmaxf(a[2] + bias.z, 0.f);
            float v3 = fmaxf(a[3] + bias.w, 0.f);
            uint2 o;
            o.x = ((unsigned int)f2bf(v0) | ((unsigned int)f2bf(v1) << 16)) & mask;
            o.y = ((unsigned int)f2bf(v2) | ((unsigned int)f2bf(v3) << 16)) & mask;
            *(uint2*)&h1L[row*132 + jb] = o;
        }
    }
    __syncthreads();

    // Phase C: tap-outer grouped conv -> h2s (LDS). Weights/bias from
    // L2-hot global (shared by all blocks).
    const int p = tid & 31;
    const int slot = tid >> 5;               // 0..7
    float acc[4][4];
    {
        float b0 = b2t[p], b1 = b2t[32+p], b2 = b2t[64+p], b3 = b2t[96+p];
#pragma unroll
        for (int i = 0; i < 4; ++i) {
            acc[i][0] = b0; acc[i][1] = b1; acc[i][2] = b2; acc[i][3] = b3;
        }
    }
#pragma unroll
    for (int ky = 0; ky < 3; ++ky) {
#pragma unroll
        for (int kx = 0; kx < 3; ++kx) {
            const float* wp = &w2q[(ky*3 + kx) * 512 + p*4];
            float4 w0 = *(const float4*)&wp[0];     // di=0
            float4 w1 = *(const float4*)&wp[128];   // di=1
            float4 w2v = *(const float4*)&wp[256];  // di=2
            float4 w3v = *(const float4*)&wp[384];  // di=3
#pragma unroll
            for (int i = 0; i < 4; ++i) {
                int nl = slot + i*8;                 // interior pos 0..31
                int hp = ((nl >> 3) + ky)*10 + (nl & 7) + kx;
                uint2 hv = *(const uint2*)&h1L[hp*132 + p*4];
                float f0 = __uint_as_float(hv.x << 16);
                float f1 = __uint_as_float(hv.x & 0xffff0000u);
                float f2 = __uint_as_float(hv.y << 16);
                float f3 = __uint_as_float(hv.y & 0xffff0000u);
                acc[i][0] = fmaf(f0, w0.x, acc[i][0]);  acc[i][1] = fmaf(f0, w0.y, acc[i][1]);
                acc[i][2] = fmaf(f0, w0.z, acc[i][2]);  acc[i][3] = fmaf(f0, w0.w, acc[i][3]);
                acc[i][0] = fmaf(f1, w1.x, acc[i][0]);  acc[i][1] = fmaf(f1, w1.y, acc[i][1]);
                acc[i][2] = fmaf(f1, w1.z, acc[i][2]);  acc[i][3] = fmaf(f1, w1.w, acc[i][3]);
                acc[i][0] = fmaf(f2, w2v.x, acc[i][0]); acc[i][1] = fmaf(f2, w2v.y, acc[i][1]);
                acc[i][2] = fmaf(f2, w2v.z, acc[i][2]); acc[i][3] = fmaf(f2, w2v.w, acc[i][3]);
                acc[i][0] = fmaf(f3, w3v.x, acc[i][0]); acc[i][1] = fmaf(f3, w3v.y, acc[i][1]);
                acc[i][2] = fmaf(f3, w3v.z, acc[i][2]); acc[i][3] = fmaf(f3, w3v.w, acc[i][3]);
            }
        }
    }
#pragma unroll
    for (int i = 0; i < 4; ++i) {
        int nl = slot + i*8;
        uint2 o;
        o.x = (unsigned int)f2bf(fmaxf(acc[i][0], 0.f)) |
              ((unsigned int)f2bf(fmaxf(acc[i][1], 0.f)) << 16);
        o.y = (unsigned int)f2bf(fmaxf(acc[i][2], 0.f)) |
              ((unsigned int)f2bf(fmaxf(acc[i][3], 0.f)) << 16);
        *(uint2*)&h2s[nl*H2S + p*4] = o;
    }
    __syncthreads();

    // Phase D: stage-3 per-path 1x1 conv via MFMA (K=8: 4 h + 1.0*bias),
    // per-path relu, accumulate over 32 paths; residual + final relu.
    // Wave wid owns c in [wid*64, wid*64+64): 4 c-tiles of 16.
    const int cb = wid * 64;
    const unsigned short* wbp;
    int pstr, cstr;
    if (quad == 0) {
        wbp = &WB[((size_t)(cb + l15)) * 8];
        pstr = C * 8;         // shorts per p
        cstr = 16 * 8;        // shorts per c-tile
    } else {
        wbp = zb;             // 16B of zeros: k-slots 8..31 contribute 0
        pstr = 0; cstr = 0;
    }

    const f32x4_t zero = (f32x4_t){0.f, 0.f, 0.f, 0.f};
    f32x4_t dacc[2][4];
#pragma unroll
    for (int ps = 0; ps < 2; ++ps)
#pragma unroll
        for (int ct = 0; ct < 4; ++ct) dacc[ps][ct] = zero;
    const unsigned int one = 0x3f80u;        // bf16 1.0 in low half

#pragma unroll 2
    for (int pp = 0; pp < 16; ++pp) {        // p = 2*pp, 2*pp+1
        uint4 h0 = *(const uint4*)&h2s[l15*H2S + pp*8];        // pass0 rows
        uint4 h1 = *(const uint4*)&h2s[(16 + l15)*H2S + pp*8]; // pass1 rows
        union au { unsigned int u[4]; bf16x8_t v; };
        au A00, A01, A10, A11;
        A00.u[0] = h0.x; A00.u[1] = h0.y; A00.u[2] = one; A00.u[3] = 0u;
        A01.u[0] = h0.z; A01.u[1] = h0.w; A01.u[2] = one; A01.u[3] = 0u;
        A10.u[0] = h1.x; A10.u[1] = h1.y; A10.u[2] = one; A10.u[3] = 0u;
        A11.u[0] = h1.z; A11.u[1] = h1.w; A11.u[2] = one; A11.u[3] = 0u;
        const unsigned short* pb0 = wbp + pp*2*pstr;
        const unsigned short* pb1 = pb0 + pstr;
#pragma unroll
        for (int ct = 0; ct < 4; ++ct) {
            union bu2 { uint4 u; bf16x8_t v; } B0, B1;
            B0.u = *(const uint4*)(pb0 + ct*cstr);
            B1.u = *(const uint4*)(pb1 + ct*cstr);
            f32x4_t z00 = __builtin_amdgcn_mfma_f32_16x16x32_bf16(A00.v, B0.v, zero, 0, 0, 0);
            f32x4_t z01 = __builtin_amdgcn_mfma_f32_16x16x32_bf16(A01.v, B1.v, zero, 0, 0, 0);
            f32x4_t z10 = __builtin_amdgcn_mfma_f32_16x16x32_bf16(A10.v, B0.v, zero, 0, 0, 0);
            f32x4_t z11 = __builtin_amdgcn_mfma_f32_16x16x32_bf16(A11.v, B1.v, zero, 0, 0, 0);
#pragma unroll
            for (int r = 0; r < 4; ++r) {
                dacc[0][ct][r] += fmaxf(z00[r], 0.f) + fmaxf(z01[r], 0.f);
                dacc[1][ct][r] += fmaxf(z10[r], 0.f) + fmaxf(z11[r], 0.f);
            }
        }
    }

    // Epilogue: out = relu(sum + x), fp32 residual.
#pragma unroll
    for (int ps = 0; ps < 2; ++ps) {
#pragma unroll
        for (int r = 0; r < 4; ++r) {
            int nl = ps*16 + quad*4 + r;
            int gy = yb*4 + (nl >> 3), gx = xb*8 + (nl & 7);
            size_t n = (size_t)((b*HH + gy)*WW + gx);
            const float* xr = &x[n*C + cb + l15];
            float* orow = &out[n*C + cb + l15];
#pragma unroll
            for (int ct = 0; ct < 4; ++ct) {
                float v = dacc[ps][ct][r] + xr[ct*16];
                orow[ct*16] = fmaxf(v, 0.f);
            }
        }
    }
}

// ---------------------------------------------------------------------------
extern "C" void kernel_launch(void* const* d_in, const int* in_sizes, int n_in,
                              void* d_out, int out_size, void* d_ws, size_t ws_size,
                              hipStream_t stream) {
    const float* x  = (const float*)d_in[0];
    const float* W1 = (const float*)d_in[1];
    const float* B1 = (const float*)d_in[2];
    const float* W2 = (const float*)d_in[3];
    const float* B2 = (const float*)d_in[4];
    const float* W3 = (const float*)d_in[5];
    const float* B3 = (const float*)d_in[6];
    const float* G1 = (const float*)d_in[7];
    const float* Be1= (const float*)d_in[8];
    const float* M1 = (const float*)d_in[9];
    const float* V1 = (const float*)d_in[10];
    const float* G2 = (const float*)d_in[11];
    const float* Be2= (const float*)d_in[12];
    const float* M2 = (const float*)d_in[13];
    const float* V2 = (const float*)d_in[14];
    const float* G3 = (const float*)d_in[15];
    const float* Be3= (const float*)d_in[16];
    const float* M3 = (const float*)d_in[17];
    const float* V3 = (const float*)d_in[18];

    char* wsb = (char*)d_ws;
    unsigned short* W1bf = (unsigned short*)(wsb + 0);        // 65,536 B
    unsigned short* WB   = (unsigned short*)(wsb + 65536);    // 131,072 B
    float*          w2q  = (float*)(wsb + 196608);            // 18,432 B
    float*          b1f  = (float*)(wsb + 215040);            // 512 B
    float*          b2t  = (float*)(wsb + 215552);            // 512 B
    unsigned short* zb   = (unsigned short*)(wsb + 216064);   // 16 B zeros

    const int fold_tasks = C*J + J + 9*D*D*P + J + P*C*8 + 8; // 103,176
    fold_params<<<(fold_tasks + 255)/256, 256, 0, stream>>>(
        W1, B1, W2, B2, W3, B3, G1, Be1, M1, V1, G2, Be2, M2, V2,
        G3, Be3, M3, V3, W1bf, b1f, w2q, b2t, WB, zb);

    fused_all<<<8*14*7, 256, 0, stream>>>(x, W1bf, b1f, w2q, b2t, WB, zb,
                                          (float*)d_out);
}

// Round 5
// 188.474 us; speedup vs baseline: 1.0478x; 1.0478x over previous
//
#include <hip/hip_runtime.h>

// Problem constants
#define BATCH 8
#define HH 56
#define WW 56
#define NPOS (BATCH*HH*WW)   // 25088
#define C 256
#define P 32
#define D 4
#define J 128
#define EPS 1e-3f
#define H2S 136   // h2s stride in shorts

typedef __attribute__((ext_vector_type(8))) short bf16x8_t;
typedef __attribute__((ext_vector_type(4))) float f32x4_t;

__device__ __forceinline__ unsigned short f2bf(float f) {
    union { float f; unsigned int i; } v; v.f = f;
    unsigned int r = v.i + 0x7fffu + ((v.i >> 16) & 1u);   // RNE
    return (unsigned short)(r >> 16);
}
__device__ __forceinline__ uint2 pack4_trunc(float4 v) {
    uint2 r;
    r.x = __builtin_amdgcn_perm(__float_as_uint(v.y), __float_as_uint(v.x), 0x07060302u);
    r.y = __builtin_amdgcn_perm(__float_as_uint(v.w), __float_as_uint(v.z), 0x07060302u);
    return r;
}

// ---------------------------------------------------------------------------
// Fold BN into conv weights/biases (unchanged).
// ---------------------------------------------------------------------------
__global__ __launch_bounds__(256) void fold_params(
    const float* __restrict__ W1, const float* __restrict__ B1,
    const float* __restrict__ W2, const float* __restrict__ B2,
    const float* __restrict__ W3, const float* __restrict__ B3,
    const float* __restrict__ G1, const float* __restrict__ Be1,
    const float* __restrict__ M1, const float* __restrict__ V1,
    const float* __restrict__ G2, const float* __restrict__ Be2,
    const float* __restrict__ M2, const float* __restrict__ V2,
    const float* __restrict__ G3, const float* __restrict__ Be3,
    const float* __restrict__ M3, const float* __restrict__ V3,
    unsigned short* __restrict__ W1bf, float* __restrict__ b1f,
    float* __restrict__ w2q, float* __restrict__ b2t,
    unsigned short* __restrict__ WB, unsigned short* __restrict__ zb)
{
    int idx = blockIdx.x * 256 + threadIdx.x;

    if (idx < C*J) {                       // W1bf[j][c]
        int j = idx >> 8, c = idx & 255;
        int p = j >> 2, d = j & 3;
        float s = G1[j] * rsqrtf(V1[j] + EPS);
        W1bf[idx] = f2bf(W1[(p*C + c)*D + d] * s);
        return;
    }
    idx -= C*J;
    if (idx < J) {
        float s = G1[idx] * rsqrtf(V1[idx] + EPS);
        b1f[idx] = B1[idx] * s + Be1[idx] - M1[idx] * s;
        return;
    }
    idx -= J;
    if (idx < 9*D*D*P) {                   // w2q [(k9*4+di)*128 + p*4 + do]
        int do_ = idx & 3, p = (idx >> 2) & 31;
        int r2 = idx >> 7, di = r2 & 3, k9 = r2 >> 2;
        int j = p*4 + do_;
        float s = G2[j] * rsqrtf(V2[j] + EPS);
        w2q[idx] = W2[((p*9 + k9)*4 + di)*4 + do_] * s;
        return;
    }
    idx -= 9*D*D*P;
    if (idx < J) {                         // b2t[do][p]
        int do_ = idx >> 5, p = idx & 31;
        int j = p*4 + do_;
        float s = G2[j] * rsqrtf(V2[j] + EPS);
        b2t[idx] = B2[j] * s + Be2[j] - M2[j] * s;
        return;
    }
    idx -= J;
    if (idx < P*C*8) {                     // WB[p][c][s] = {w0..w3, bias, 0,0,0}
        int s8 = idx & 7;
        int c = (idx >> 3) & 255;
        int p = idx >> 11;
        float sc = G3[p*C + c] * rsqrtf(V3[p*C + c] + EPS);
        float v = 0.f;
        if (s8 < 4)       v = W3[(p*D + s8)*C + c] * sc;
        else if (s8 == 4) v = B3[p*C + c] * sc + Be3[p*C + c] - M3[p*C + c] * sc;
        WB[idx] = f2bf(v);
        return;
    }
    idx -= P*C*8;
    if (idx < 8) { zb[idx] = 0; return; }  // 16B zero block
}

// ---------------------------------------------------------------------------
// Fully fused, small-tile/high-occupancy version.
// Tile: 4y x 4x interior, 6x6 halo (36 pos). Grid: 8*14*14 = 1568 blocks.
// LDS 27.9 KB (xs 18.4K + h1L 9.5K; h2s aliases dead xs) -> 5 blocks/CU.
// Phase A: x halo -> LDS bf16 (swizzled). Phase B: s1 MFMA (jf-outer, aw=32
// VGPR). Phase C: grouped 3x3 VALU, weights from L2-hot global. Phase D:
// s3 MFMA per-path-relu accumulate + residual + relu.
// ---------------------------------------------------------------------------
__global__ __launch_bounds__(256) void fused_all(
    const float* __restrict__ x, const unsigned short* __restrict__ W1bf,
    const float* __restrict__ b1f, const float* __restrict__ w2q,
    const float* __restrict__ b2t, const unsigned short* __restrict__ WB,
    const unsigned short* __restrict__ zb, float* __restrict__ out)
{
    __shared__ unsigned short smem[36*256 + 36*132];   // 27,936 B
    unsigned short* xs  = smem;            // [36][256], swizzled; dead after B
    unsigned short* h1L = smem + 36*256;   // [36][132]
    unsigned short* h2s = smem;            // [16][136], aliases xs

    const int tid = threadIdx.x;
    int bxx = blockIdx.x;
    const int xb = bxx % 14;  bxx /= 14;
    const int yb = bxx % 14;  const int b = bxx / 14;
    const int wid = tid >> 6, l = tid & 63, l15 = l & 15, quad = l >> 4;
    const int j0w = wid * 32;

    // Phase A: stage x halo (36 pos x 256 ch), fp32->bf16, XOR-swizzled
#pragma unroll
    for (int it = 0; it < 5; ++it) {
        int idx = it*256 + tid;              // 1152 tasks
        int pos = idx >> 5, g = idx & 31;
        if (pos < 36) {
            int hy = (pos*43) >> 8, hx = pos - hy*6;     // pos/6 for pos<48
            int gy = yb*4 + hy - 1, gx = xb*4 + hx - 1;
            uint4 st; st.x = 0u; st.y = 0u; st.z = 0u; st.w = 0u;
            if (gy >= 0 && gy < HH && gx >= 0 && gx < WW) {
                const float* xp = &x[(size_t)((b*HH + gy)*WW + gx) * C + g*8];
                float4 v0 = *(const float4*)xp;
                float4 v1 = *(const float4*)(xp + 4);
                uint2 p0 = pack4_trunc(v0), p1 = pack4_trunc(v1);
                st.x = p0.x; st.y = p0.y; st.z = p1.x; st.w = p1.y;
            }
            *(uint4*)&xs[pos*256 + ((g ^ (pos & 7)) * 8)] = st;
        }
    }
    __syncthreads();

    // Phase B: s1 GEMM -> h1L, jf-outer (half the aw registers).
    union bu { uint4 u; bf16x8_t v; };
#pragma unroll
    for (int jf = 0; jf < 2; ++jf) {
        bu aw[8];
        const int wrow = j0w + jf*16 + l15;
#pragma unroll
        for (int kc = 0; kc < 8; ++kc)
            aw[kc].u = *(const uint4*)&W1bf[wrow*C + kc*32 + quad*8];
#pragma unroll
        for (int mt = 0; mt < 3; ++mt) {
            const int row = mt*16 + l15;     // halo pos (B col), 0..47
            const int rrow = (row < 36) ? row : 0;   // clamp for LDS reads
            int hy = (row*43) >> 8;          // row/6, valid to 47
            int hx = row - hy*6;
            int gy = yb*4 + hy - 1, gx = xb*4 + hx - 1;
            const bool valid = (row < 36) & (gy >= 0) & (gy < HH) & (gx >= 0) & (gx < WW);
            const unsigned mask = valid ? 0xFFFFFFFFu : 0u;
            f32x4_t acc = (f32x4_t){0.f,0.f,0.f,0.f};
#pragma unroll
            for (int kc = 0; kc < 8; ++kc) {
                int g = (kc*4 + quad) ^ (rrow & 7);
                bf16x8_t bb = *(const bf16x8_t*)&xs[rrow*256 + g*8];
                acc = __builtin_amdgcn_mfma_f32_16x16x32_bf16(aw[kc].v, bb, acc, 0, 0, 0);
            }
            if (row < 36) {
                int jb = j0w + jf*16 + quad*4;
                float4 bias = *(const float4*)&b1f[jb];   // global, L2-hot
                float v0 = fmaxf(acc[0] + bias.x, 0.f);
                float v1 = fmaxf(acc[1] + bias.y, 0.f);
                float v2 = fmaxf(acc[2] + bias.z, 0.f);
                float v3 = fmaxf(acc[3] + bias.w, 0.f);
                uint2 o;
                o.x = ((unsigned int)f2bf(v0) | ((unsigned int)f2bf(v1) << 16)) & mask;
                o.y = ((unsigned int)f2bf(v2) | ((unsigned int)f2bf(v3) << 16)) & mask;
                *(uint2*)&h1L[row*132 + jb] = o;
            }
        }
    }
    __syncthreads();

    // Phase C: tap-outer grouped conv (16 interior pos) -> h2s (aliases xs).
    const int p = tid & 31;
    const int slot = tid >> 5;               // 0..7
    float acc[2][4];
    {
        float b0 = b2t[p], b1 = b2t[32+p], b2 = b2t[64+p], b3 = b2t[96+p];
#pragma unroll
        for (int i = 0; i < 2; ++i) {
            acc[i][0] = b0; acc[i][1] = b1; acc[i][2] = b2; acc[i][3] = b3;
        }
    }
#pragma unroll
    for (int ky = 0; ky < 3; ++ky) {
#pragma unroll
        for (int kx = 0; kx < 3; ++kx) {
            const float* wp = &w2q[(ky*3 + kx) * 512 + p*4];
            float4 w0 = *(const float4*)&wp[0];     // di=0
            float4 w1 = *(const float4*)&wp[128];   // di=1
            float4 w2v = *(const float4*)&wp[256];  // di=2
            float4 w3v = *(const float4*)&wp[384];  // di=3
#pragma unroll
            for (int i = 0; i < 2; ++i) {
                int nl = slot + i*8;                 // interior pos 0..15
                int hp = ((nl >> 2) + ky)*6 + (nl & 3) + kx;
                uint2 hv = *(const uint2*)&h1L[hp*132 + p*4];
                float f0 = __uint_as_float(hv.x << 16);
                float f1 = __uint_as_float(hv.x & 0xffff0000u);
                float f2 = __uint_as_float(hv.y << 16);
                float f3 = __uint_as_float(hv.y & 0xffff0000u);
                acc[i][0] = fmaf(f0, w0.x, acc[i][0]);  acc[i][1] = fmaf(f0, w0.y, acc[i][1]);
                acc[i][2] = fmaf(f0, w0.z, acc[i][2]);  acc[i][3] = fmaf(f0, w0.w, acc[i][3]);
                acc[i][0] = fmaf(f1, w1.x, acc[i][0]);  acc[i][1] = fmaf(f1, w1.y, acc[i][1]);
                acc[i][2] = fmaf(f1, w1.z, acc[i][2]);  acc[i][3] = fmaf(f1, w1.w, acc[i][3]);
                acc[i][0] = fmaf(f2, w2v.x, acc[i][0]); acc[i][1] = fmaf(f2, w2v.y, acc[i][1]);
                acc[i][2] = fmaf(f2, w2v.z, acc[i][2]); acc[i][3] = fmaf(f2, w2v.w, acc[i][3]);
                acc[i][0] = fmaf(f3, w3v.x, acc[i][0]); acc[i][1] = fmaf(f3, w3v.y, acc[i][1]);
                acc[i][2] = fmaf(f3, w3v.z, acc[i][2]); acc[i][3] = fmaf(f3, w3v.w, acc[i][3]);
            }
        }
    }
    __syncthreads();   // all h1L reads done; xs long dead -> safe to write h2s
#pragma unroll
    for (int i = 0; i < 2; ++i) {
        int nl = slot + i*8;
        uint2 o;
        o.x = (unsigned int)f2bf(fmaxf(acc[i][0], 0.f)) |
              ((unsigned int)f2bf(fmaxf(acc[i][1], 0.f)) << 16);
        o.y = (unsigned int)f2bf(fmaxf(acc[i][2], 0.f)) |
              ((unsigned int)f2bf(fmaxf(acc[i][3], 0.f)) << 16);
        *(uint2*)&h2s[nl*H2S + p*4] = o;
    }
    __syncthreads();

    // Phase D: stage-3 per-path 1x1 conv via MFMA (K=8: 4 h + 1.0*bias),
    // per-path relu, accumulate over 32 paths; residual + final relu.
    // Wave wid owns c in [wid*64, wid*64+64): 4 c-tiles of 16. M=16 pos.
    const int cb = wid * 64;
    const unsigned short* wbp;
    int pstr, cstr;
    if (quad == 0) {
        wbp = &WB[((size_t)(cb + l15)) * 8];
        pstr = C * 8;         // shorts per p
        cstr = 16 * 8;        // shorts per c-tile
    } else {
        wbp = zb;             // 16B of zeros: k-slots 8..31 contribute 0
        pstr = 0; cstr = 0;
    }

    const f32x4_t zero = (f32x4_t){0.f, 0.f, 0.f, 0.f};
    f32x4_t dacc[4];
#pragma unroll
    for (int ct = 0; ct < 4; ++ct) dacc[ct] = zero;
    const unsigned int one = 0x3f80u;        // bf16 1.0 in low half

#pragma unroll 2
    for (int pp = 0; pp < 16; ++pp) {        // p = 2*pp, 2*pp+1
        uint4 h0 = *(const uint4*)&h2s[l15*H2S + pp*8];
        union au { unsigned int u[4]; bf16x8_t v; };
        au A0, A1;
        A0.u[0] = h0.x; A0.u[1] = h0.y; A0.u[2] = one; A0.u[3] = 0u;
        A1.u[0] = h0.z; A1.u[1] = h0.w; A1.u[2] = one; A1.u[3] = 0u;
        const unsigned short* pb0 = wbp + pp*2*pstr;
        const unsigned short* pb1 = pb0 + pstr;
#pragma unroll
        for (int ct = 0; ct < 4; ++ct) {
            union bu2 { uint4 u; bf16x8_t v; } B0, B1;
            B0.u = *(const uint4*)(pb0 + ct*cstr);
            B1.u = *(const uint4*)(pb1 + ct*cstr);
            f32x4_t z0 = __builtin_amdgcn_mfma_f32_16x16x32_bf16(A0.v, B0.v, zero, 0, 0, 0);
            f32x4_t z1 = __builtin_amdgcn_mfma_f32_16x16x32_bf16(A1.v, B1.v, zero, 0, 0, 0);
#pragma unroll
            for (int r = 0; r < 4; ++r)
                dacc[ct][r] += fmaxf(z0[r], 0.f) + fmaxf(z1[r], 0.f);
        }
    }

    // Epilogue: out = relu(sum + x), fp32 residual.
#pragma unroll
    for (int r = 0; r < 4; ++r) {
        int nl = quad*4 + r;                 // interior pos 0..15
        int gy = yb*4 + (nl >> 2), gx = xb*4 + (nl & 3);
        size_t n = (size_t)((b*HH + gy)*WW + gx);
        const float* xr = &x[n*C + cb + l15];
        float* orow = &out[n*C + cb + l15];
#pragma unroll
        for (int ct = 0; ct < 4; ++ct) {
            float v = dacc[ct][r] + xr[ct*16];
            orow[ct*16] = fmaxf(v, 0.f);
        }
    }
}

// ---------------------------------------------------------------------------
extern "C" void kernel_launch(void* const* d_in, const int* in_sizes, int n_in,
                              void* d_out, int out_size, void* d_ws, size_t ws_size,
                              hipStream_t stream) {
    const float* x  = (const float*)d_in[0];
    const float* W1 = (const float*)d_in[1];
    const float* B1 = (const float*)d_in[2];
    const float* W2 = (const float*)d_in[3];
    const float* B2 = (const float*)d_in[4];
    const float* W3 = (const float*)d_in[5];
    const float* B3 = (const float*)d_in[6];
    const float* G1 = (const float*)d_in[7];
    const float* Be1= (const float*)d_in[8];
    const float* M1 = (const float*)d_in[9];
    const float* V1 = (const float*)d_in[10];
    const float* G2 = (const float*)d_in[11];
    const float* Be2= (const float*)d_in[12];
    const float* M2 = (const float*)d_in[13];
    const float* V2 = (const float*)d_in[14];
    const float* G3 = (const float*)d_in[15];
    const float* Be3= (const float*)d_in[16];
    const float* M3 = (const float*)d_in[17];
    const float* V3 = (const float*)d_in[18];

    char* wsb = (char*)d_ws;
    unsigned short* W1bf = (unsigned short*)(wsb + 0);        // 65,536 B
    unsigned short* WB   = (unsigned short*)(wsb + 65536);    // 131,072 B
    float*          w2q  = (float*)(wsb + 196608);            // 18,432 B
    float*          b1f  = (float*)(wsb + 215040);            // 512 B
    float*          b2t  = (float*)(wsb + 215552);            // 512 B
    unsigned short* zb   = (unsigned short*)(wsb + 216064);   // 16 B zeros

    const int fold_tasks = C*J + J + 9*D*D*P + J + P*C*8 + 8; // 103,176
    fold_params<<<(fold_tasks + 255)/256, 256, 0, stream>>>(
        W1, B1, W2, B2, W3, B3, G1, Be1, M1, V1, G2, Be2, M2, V2,
        G3, Be3, M3, V3, W1bf, b1f, w2q, b2t, WB, zb);

    fused_all<<<8*14*14, 256, 0, stream>>>(x, W1bf, b1f, w2q, b2t, WB, zb,
                                           (float*)d_out);
}

// Round 6
// 175.717 us; speedup vs baseline: 1.1238x; 1.0726x over previous
//
#include <hip/hip_runtime.h>

// Problem constants
#define BATCH 8
#define HH 56
#define WW 56
#define NPOS (BATCH*HH*WW)   // 25088
#define C 256
#define P 32
#define D 4
#define J 128
#define EPS 1e-3f
#define H2S 136   // h2s stride in shorts

typedef __attribute__((ext_vector_type(8))) short bf16x8_t;
typedef __attribute__((ext_vector_type(4))) float f32x4_t;

__device__ __forceinline__ unsigned short f2bf(float f) {
    union { float f; unsigned int i; } v; v.f = f;
    unsigned int r = v.i + 0x7fffu + ((v.i >> 16) & 1u);   // RNE
    return (unsigned short)(r >> 16);
}
__device__ __forceinline__ uint2 pack4_trunc(float4 v) {
    uint2 r;
    r.x = __builtin_amdgcn_perm(__float_as_uint(v.y), __float_as_uint(v.x), 0x07060302u);
    r.y = __builtin_amdgcn_perm(__float_as_uint(v.w), __float_as_uint(v.z), 0x07060302u);
    return r;
}

// ---------------------------------------------------------------------------
// Fold BN into conv weights/biases (unchanged).
// ---------------------------------------------------------------------------
__global__ __launch_bounds__(256) void fold_params(
    const float* __restrict__ W1, const float* __restrict__ B1,
    const float* __restrict__ W2, const float* __restrict__ B2,
    const float* __restrict__ W3, const float* __restrict__ B3,
    const float* __restrict__ G1, const float* __restrict__ Be1,
    const float* __restrict__ M1, const float* __restrict__ V1,
    const float* __restrict__ G2, const float* __restrict__ Be2,
    const float* __restrict__ M2, const float* __restrict__ V2,
    const float* __restrict__ G3, const float* __restrict__ Be3,
    const float* __restrict__ M3, const float* __restrict__ V3,
    unsigned short* __restrict__ W1bf, float* __restrict__ b1f,
    float* __restrict__ w2q, float* __restrict__ b2t,
    unsigned short* __restrict__ WB, unsigned short* __restrict__ zb)
{
    int idx = blockIdx.x * 256 + threadIdx.x;

    if (idx < C*J) {                       // W1bf[j][c]
        int j = idx >> 8, c = idx & 255;
        int p = j >> 2, d = j & 3;
        float s = G1[j] * rsqrtf(V1[j] + EPS);
        W1bf[idx] = f2bf(W1[(p*C + c)*D + d] * s);
        return;
    }
    idx -= C*J;
    if (idx < J) {
        float s = G1[idx] * rsqrtf(V1[idx] + EPS);
        b1f[idx] = B1[idx] * s + Be1[idx] - M1[idx] * s;
        return;
    }
    idx -= J;
    if (idx < 9*D*D*P) {                   // w2q [(k9*4+di)*128 + p*4 + do]
        int do_ = idx & 3, p = (idx >> 2) & 31;
        int r2 = idx >> 7, di = r2 & 3, k9 = r2 >> 2;
        int j = p*4 + do_;
        float s = G2[j] * rsqrtf(V2[j] + EPS);
        w2q[idx] = W2[((p*9 + k9)*4 + di)*4 + do_] * s;
        return;
    }
    idx -= 9*D*D*P;
    if (idx < J) {                         // b2t[do][p]
        int do_ = idx >> 5, p = idx & 31;
        int j = p*4 + do_;
        float s = G2[j] * rsqrtf(V2[j] + EPS);
        b2t[idx] = B2[j] * s + Be2[j] - M2[j] * s;
        return;
    }
    idx -= J;
    if (idx < P*C*8) {                     // WB[p][c][s] = {w0..w3, bias, 0,0,0}
        int s8 = idx & 7;
        int c = (idx >> 3) & 255;
        int p = idx >> 11;
        float sc = G3[p*C + c] * rsqrtf(V3[p*C + c] + EPS);
        float v = 0.f;
        if (s8 < 4)       v = W3[(p*D + s8)*C + c] * sc;
        else if (s8 == 4) v = B3[p*C + c] * sc + Be3[p*C + c] - M3[p*C + c] * sc;
        WB[idx] = f2bf(v);
        return;
    }
    idx -= P*C*8;
    if (idx < 8) { zb[idx] = 0; return; }  // 16B zero block
}

// ---------------------------------------------------------------------------
// Fully fused, 2-barrier version. Tile 4x4 interior, 6x6 halo (36 pos).
// Grid 1568 blocks (XCD-swizzled: each XCD owns one batch image).
// Wave-local pipeline: wave w produces h1 for j in [32w,32w+32) (phase B)
// and consumes exactly that range in phase C (paths p in [8w,8w+8)) -> no
// barrier between B and C, none before the h2s write (h2s not aliased).
// Barriers: A->B (xs cross-wave), h2s->D (h2 cross-wave). LDS 32.3 KB ->
// 4 blocks/CU; __launch_bounds__(256,4) -> 128 VGPR for load hoisting.
// ---------------------------------------------------------------------------
__global__ __launch_bounds__(256, 4) void fused_all(
    const float* __restrict__ x, const unsigned short* __restrict__ W1bf,
    const float* __restrict__ b1f, const float* __restrict__ w2q,
    const float* __restrict__ b2t, const unsigned short* __restrict__ WB,
    const unsigned short* __restrict__ zb, float* __restrict__ out)
{
    __shared__ unsigned short xs[36*256];    // 18,432 B, swizzled
    __shared__ unsigned short h1L[36*132];   //  9,504 B  [pos][j]
    __shared__ unsigned short h2s[16*H2S];   //  4,352 B  [pos][j]

    const int tid = threadIdx.x;
    // XCD-aware swizzle: 1568 = 8 xcd * 196; 196 = one 14x14 image.
    int bid = blockIdx.x;
    int wg = (bid & 7) * 196 + (bid >> 3);
    const int xb = wg % 14;  wg /= 14;
    const int yb = wg % 14;  const int b = wg / 14;
    const int wid = tid >> 6, l = tid & 63, l15 = l & 15, quad = l >> 4;
    const int j0w = wid * 32;

    // Phase A: stage x halo (36 pos x 256 ch), fp32->bf16, XOR-swizzled
#pragma unroll
    for (int it = 0; it < 5; ++it) {
        int idx = it*256 + tid;              // 1152 tasks
        int pos = idx >> 5, g = idx & 31;
        if (pos < 36) {
            int hy = (pos*43) >> 8, hx = pos - hy*6;     // pos/6
            int gy = yb*4 + hy - 1, gx = xb*4 + hx - 1;
            uint4 st; st.x = 0u; st.y = 0u; st.z = 0u; st.w = 0u;
            if (gy >= 0 && gy < HH && gx >= 0 && gx < WW) {
                const float* xp = &x[(size_t)((b*HH + gy)*WW + gx) * C + g*8];
                float4 v0 = *(const float4*)xp;
                float4 v1 = *(const float4*)(xp + 4);
                uint2 p0 = pack4_trunc(v0), p1 = pack4_trunc(v1);
                st.x = p0.x; st.y = p0.y; st.z = p1.x; st.w = p1.y;
            }
            *(uint4*)&xs[pos*256 + ((g ^ (pos & 7)) * 8)] = st;
        }
    }
    __syncthreads();

    // Phase B: s1 GEMM -> h1L (wave-private j range), jf-outer.
    union bu { uint4 u; bf16x8_t v; };
#pragma unroll
    for (int jf = 0; jf < 2; ++jf) {
        bu aw[8];
        const int wrow = j0w + jf*16 + l15;
#pragma unroll
        for (int kc = 0; kc < 8; ++kc)
            aw[kc].u = *(const uint4*)&W1bf[wrow*C + kc*32 + quad*8];
#pragma unroll
        for (int mt = 0; mt < 3; ++mt) {
            const int row = mt*16 + l15;     // halo pos (B col), 0..47
            const int rrow = (row < 36) ? row : 0;   // clamp for LDS reads
            int hy = (row*43) >> 8;          // row/6
            int hx = row - hy*6;
            int gy = yb*4 + hy - 1, gx = xb*4 + hx - 1;
            const bool valid = (row < 36) & (gy >= 0) & (gy < HH) & (gx >= 0) & (gx < WW);
            const unsigned mask = valid ? 0xFFFFFFFFu : 0u;
            f32x4_t acc = (f32x4_t){0.f,0.f,0.f,0.f};
#pragma unroll
            for (int kc = 0; kc < 8; ++kc) {
                int g = (kc*4 + quad) ^ (rrow & 7);
                bf16x8_t bb = *(const bf16x8_t*)&xs[rrow*256 + g*8];
                acc = __builtin_amdgcn_mfma_f32_16x16x32_bf16(aw[kc].v, bb, acc, 0, 0, 0);
            }
            if (row < 36) {
                int jb = j0w + jf*16 + quad*4;
                float4 bias = *(const float4*)&b1f[jb];   // global, L2-hot
                float v0 = fmaxf(acc[0] + bias.x, 0.f);
                float v1 = fmaxf(acc[1] + bias.y, 0.f);
                float v2 = fmaxf(acc[2] + bias.z, 0.f);
                float v3 = fmaxf(acc[3] + bias.w, 0.f);
                uint2 o;
                o.x = ((unsigned int)f2bf(v0) | ((unsigned int)f2bf(v1) << 16)) & mask;
                o.y = ((unsigned int)f2bf(v2) | ((unsigned int)f2bf(v3) << 16)) & mask;
                *(uint2*)&h1L[row*132 + jb] = o;
            }
        }
    }
    // NO barrier: wave w reads back only the h1L columns it just wrote.

    // Phase C: grouped 3x3 conv, wave-local paths p in [8w, 8w+8).
    // Lane: pos = l&15 (4x4 interior), q-pair = l>>4; i in {0,1}.
    const int pos = l15;
    const int py = pos >> 2, px = pos & 3;
#pragma unroll
    for (int i = 0; i < 2; ++i) {
        const int q = (l >> 4) * 2 + i;
        const int p = wid*8 + q;
        float a0 = b2t[p], a1 = b2t[32+p], a2 = b2t[64+p], a3 = b2t[96+p];
#pragma unroll
        for (int ky = 0; ky < 3; ++ky) {
#pragma unroll
            for (int kx = 0; kx < 3; ++kx) {
                const float* wp = &w2q[(ky*3 + kx) * 512 + p*4];
                float4 w0 = *(const float4*)&wp[0];     // di=0
                float4 w1 = *(const float4*)&wp[128];   // di=1
                float4 w2v = *(const float4*)&wp[256];  // di=2
                float4 w3v = *(const float4*)&wp[384];  // di=3
                int hp = (py + ky)*6 + px + kx;
                uint2 hv = *(const uint2*)&h1L[hp*132 + p*4];
                float f0 = __uint_as_float(hv.x << 16);
                float f1 = __uint_as_float(hv.x & 0xffff0000u);
                float f2 = __uint_as_float(hv.y << 16);
                float f3 = __uint_as_float(hv.y & 0xffff0000u);
                a0 = fmaf(f0, w0.x, a0);  a1 = fmaf(f0, w0.y, a1);
                a2 = fmaf(f0, w0.z, a2);  a3 = fmaf(f0, w0.w, a3);
                a0 = fmaf(f1, w1.x, a0);  a1 = fmaf(f1, w1.y, a1);
                a2 = fmaf(f1, w1.z, a2);  a3 = fmaf(f1, w1.w, a3);
                a0 = fmaf(f2, w2v.x, a0); a1 = fmaf(f2, w2v.y, a1);
                a2 = fmaf(f2, w2v.z, a2); a3 = fmaf(f2, w2v.w, a3);
                a0 = fmaf(f3, w3v.x, a0); a1 = fmaf(f3, w3v.y, a1);
                a2 = fmaf(f3, w3v.z, a2); a3 = fmaf(f3, w3v.w, a3);
            }
        }
        uint2 o;
        o.x = (unsigned int)f2bf(fmaxf(a0, 0.f)) |
              ((unsigned int)f2bf(fmaxf(a1, 0.f)) << 16);
        o.y = (unsigned int)f2bf(fmaxf(a2, 0.f)) |
              ((unsigned int)f2bf(fmaxf(a3, 0.f)) << 16);
        *(uint2*)&h2s[pos*H2S + p*4] = o;
    }
    __syncthreads();

    // Phase D: stage-3 per-path 1x1 conv via MFMA (K=8: 4 h + 1.0*bias),
    // per-path relu, accumulate over 32 paths; residual + final relu.
    // Wave wid owns c in [wid*64, wid*64+64): 4 c-tiles of 16. M=16 pos.
    const int cb = wid * 64;
    const unsigned short* wbp;
    int pstr, cstr;
    if (quad == 0) {
        wbp = &WB[((size_t)(cb + l15)) * 8];
        pstr = C * 8;         // shorts per p
        cstr = 16 * 8;        // shorts per c-tile
    } else {
        wbp = zb;             // 16B of zeros: k-slots 8..31 contribute 0
        pstr = 0; cstr = 0;
    }

    const f32x4_t zero = (f32x4_t){0.f, 0.f, 0.f, 0.f};
    f32x4_t dacc[4];
#pragma unroll
    for (int ct = 0; ct < 4; ++ct) dacc[ct] = zero;
    const unsigned int one = 0x3f80u;        // bf16 1.0 in low half

#pragma unroll 2
    for (int pp = 0; pp < 16; ++pp) {        // p = 2*pp, 2*pp+1
        uint4 h0 = *(const uint4*)&h2s[l15*H2S + pp*8];
        union au { unsigned int u[4]; bf16x8_t v; };
        au A0, A1;
        A0.u[0] = h0.x; A0.u[1] = h0.y; A0.u[2] = one; A0.u[3] = 0u;
        A1.u[0] = h0.z; A1.u[1] = h0.w; A1.u[2] = one; A1.u[3] = 0u;
        const unsigned short* pb0 = wbp + pp*2*pstr;
        const unsigned short* pb1 = pb0 + pstr;
#pragma unroll
        for (int ct = 0; ct < 4; ++ct) {
            union bu2 { uint4 u; bf16x8_t v; } B0, B1;
            B0.u = *(const uint4*)(pb0 + ct*cstr);
            B1.u = *(const uint4*)(pb1 + ct*cstr);
            f32x4_t z0 = __builtin_amdgcn_mfma_f32_16x16x32_bf16(A0.v, B0.v, zero, 0, 0, 0);
            f32x4_t z1 = __builtin_amdgcn_mfma_f32_16x16x32_bf16(A1.v, B1.v, zero, 0, 0, 0);
#pragma unroll
            for (int r = 0; r < 4; ++r)
                dacc[ct][r] += fmaxf(z0[r], 0.f) + fmaxf(z1[r], 0.f);
        }
    }

    // Epilogue: out = relu(sum + x), fp32 residual.
#pragma unroll
    for (int r = 0; r < 4; ++r) {
        int nl = quad*4 + r;                 // interior pos 0..15
        int gy = yb*4 + (nl >> 2), gx = xb*4 + (nl & 3);
        size_t n = (size_t)((b*HH + gy)*WW + gx);
        const float* xr = &x[n*C + cb + l15];
        float* orow = &out[n*C + cb + l15];
#pragma unroll
        for (int ct = 0; ct < 4; ++ct) {
            float v = dacc[ct][r] + xr[ct*16];
            orow[ct*16] = fmaxf(v, 0.f);
        }
    }
}

// ---------------------------------------------------------------------------
extern "C" void kernel_launch(void* const* d_in, const int* in_sizes, int n_in,
                              void* d_out, int out_size, void* d_ws, size_t ws_size,
                              hipStream_t stream) {
    const float* x  = (const float*)d_in[0];
    const float* W1 = (const float*)d_in[1];
    const float* B1 = (const float*)d_in[2];
    const float* W2 = (const float*)d_in[3];
    const float* B2 = (const float*)d_in[4];
    const float* W3 = (const float*)d_in[5];
    const float* B3 = (const float*)d_in[6];
    const float* G1 = (const float*)d_in[7];
    const float* Be1= (const float*)d_in[8];
    const float* M1 = (const float*)d_in[9];
    const float* V1 = (const float*)d_in[10];
    const float* G2 = (const float*)d_in[11];
    const float* Be2= (const float*)d_in[12];
    const float* M2 = (const float*)d_in[13];
    const float* V2 = (const float*)d_in[14];
    const float* G3 = (const float*)d_in[15];
    const float* Be3= (const float*)d_in[16];
    const float* M3 = (const float*)d_in[17];
    const float* V3 = (const float*)d_in[18];

    char* wsb = (char*)d_ws;
    unsigned short* W1bf = (unsigned short*)(wsb + 0);        // 65,536 B
    unsigned short* WB   = (unsigned short*)(wsb + 65536);    // 131,072 B
    float*          w2q  = (float*)(wsb + 196608);            // 18,432 B
    float*          b1f  = (float*)(wsb + 215040);            // 512 B
    float*          b2t  = (float*)(wsb + 215552);            // 512 B
    unsigned short* zb   = (unsigned short*)(wsb + 216064);   // 16 B zeros

    const int fold_tasks = C*J + J + 9*D*D*P + J + P*C*8 + 8; // 103,176
    fold_params<<<(fold_tasks + 255)/256, 256, 0, stream>>>(
        W1, B1, W2, B2, W3, B3, G1, Be1, M1, V1, G2, Be2, M2, V2,
        G3, Be3, M3, V3, W1bf, b1f, w2q, b2t, WB, zb);

    fused_all<<<8*14*14, 256, 0, stream>>>(x, W1bf, b1f, w2q, b2t, WB, zb,
                                           (float*)d_out);
}